// Round 20
// baseline (1072.736 us; speedup 1.0000x reference)
//
#include <hip/hip_runtime.h>
#include <hip/hip_bf16.h>

#define T_SEQ 2048
#define BATCH 2
#define CDIM 1024
#define VDIM 256
#define NHEAD 16
#define DHEAD 64
#define NLAYER 8
#define MROWS (BATCH * T_SEQ) /* 4096 */

typedef __attribute__((ext_vector_type(8))) short bf16x8;
typedef __attribute__((ext_vector_type(4))) float f32x4;
typedef __attribute__((ext_vector_type(4))) int i32x4;

#define SELHI 0x07060302u
#define SELLO 0x05040100u
#define QSCALE 0.18033688011112042f  /* 0.125 * log2(e) */

__device__ __forceinline__ uint prm(uint a, uint b, uint s) { return __builtin_amdgcn_perm(a, b, s); }

__device__ __forceinline__ uint bf16rne(float f) {
    uint u = __float_as_uint(f);
    return (u + 0x7fffu + ((u >> 16) & 1u)) & 0xffff0000u;
}
__device__ __forceinline__ uint packsplit(float x) {
    uint hb = bf16rne(x);
    float d = x - __uint_as_float(hb);
    uint lb = bf16rne(d);
    return prm(hb, lb, SELHI);
}
__device__ __forceinline__ float unpack2(uint u) {
    return __uint_as_float(u & 0xffff0000u) + __uint_as_float(u << 16);
}
__device__ __forceinline__ bf16x8 asb(i32x4 v) {
    union { i32x4 i; bf16x8 b; } u; u.i = v; return u.b;
}
__device__ __forceinline__ short bfs(float f) { return (short)(bf16rne(f) >> 16); }
// async global->LDS DMA, 16B per lane: lds slot = uniform base + lane*16
__device__ __forceinline__ void gload_lds16(const void* g, void* l) {
    __builtin_amdgcn_global_load_lds(
        (const __attribute__((address_space(1))) void*)g,
        (__attribute__((address_space(3))) void*)l, 16, 0, 0);
}

// Frag-packed u32 activation layout for X[M][K] (K mult of 32):
//   slot(m,k) = ((m>>4)*(K>>5)+(k>>5))*512 + (((k>>2)&3)*16+(m&15))*8 + (k&3)+4*((k>>4)&1)
// Hi-only bf16 frag layout (A-operand direct):
//   slot(m,k) = (((m>>4)*(K>>5)+(k>>5))*64 + ((k>>2)&3)*16 + (m&15))*8 + (k&3)+4*((k>>4)&1)

// ---------------------------------------------------------------------------
// Pack x (f32 rows, K=256) -> frag-packed hi|lo u32.
// ---------------------------------------------------------------------------
__global__ __launch_bounds__(256) void packx_kernel(
    const float* __restrict__ x, uint* __restrict__ xpf)
{
    const int t  = blockIdx.x * 256 + threadIdx.x;   // 0 .. 4096*64-1
    const int m  = t >> 6;
    const int k0 = (t & 63) * 4;
    const float4 v = *(const float4*)&x[(size_t)m * 256 + k0];
    const size_t addr = ((size_t)(m >> 4) * 8 + (k0 >> 5)) * 512
                      + (size_t)(((k0 >> 2) & 3) * 16 + (m & 15)) * 8
                      + 4 * ((k0 >> 4) & 1);
    uint4 pk;
    pk.x = packsplit(v.x); pk.y = packsplit(v.y);
    pk.z = packsplit(v.z); pk.w = packsplit(v.w);
    *(uint4*)&xpf[addr] = pk;
}

// ---------------------------------------------------------------------------
// Weight pre-split: W[K][N] f32 -> frag-order hi (and optionally lo) bf16.
// ---------------------------------------------------------------------------
__device__ __forceinline__ void wsplit_body(
    const float* __restrict__ W, short* __restrict__ Fh, short* __restrict__ Fl,
    int N, int K, int n, int kq)
{
    const int k0 = kq * 4;
    float f0 = W[(size_t)(k0 + 0) * N + n];
    float f1 = W[(size_t)(k0 + 1) * N + n];
    float f2 = W[(size_t)(k0 + 2) * N + n];
    float f3 = W[(size_t)(k0 + 3) * N + n];
    uint h0 = bf16rne(f0), h1 = bf16rne(f1), h2 = bf16rne(f2), h3 = bf16rne(f3);

    const int gl = kq & 3, j0 = ((kq >> 2) & 1) * 4;
    const size_t base = (((size_t)(n >> 4) * (K >> 5) + (kq >> 3)) * 64 + gl * 16 + (n & 15)) * 8 + j0;
    *(int2*)&Fh[base] = make_int2((int)prm(h1, h0, SELHI), (int)prm(h3, h2, SELHI));
    if (Fl) {
        uint l0 = bf16rne(f0 - __uint_as_float(h0));
        uint l1 = bf16rne(f1 - __uint_as_float(h1));
        uint l2 = bf16rne(f2 - __uint_as_float(h2));
        uint l3 = bf16rne(f3 - __uint_as_float(h3));
        *(int2*)&Fl[base] = make_int2((int)prm(l1, l0, SELHI), (int)prm(l3, l2, SELHI));
    }
}

__global__ __launch_bounds__(256) void wsplit_kernel(
    const float* __restrict__ W, short* __restrict__ Fh, short* __restrict__ Fl,
    int N, int K)
{
    const int ln = threadIdx.x & 63, lk = threadIdx.x >> 6;
    wsplit_body(W, Fh, Fl, N, K, blockIdx.x * 64 + ln, blockIdx.y * 4 + lk);
}

// Fused per-layer split: Wqkv (hi only, N=3072) + Wproj (hi+lo, N=1024), K=1024.
__global__ __launch_bounds__(256) void wsplit2_kernel(
    const float* __restrict__ Wq, short* __restrict__ Fqh,
    const float* __restrict__ Wp, short* __restrict__ Fph, short* __restrict__ Fpl)
{
    const int ln = threadIdx.x & 63, lk = threadIdx.x >> 6;
    const int kq = blockIdx.y * 4 + lk;
    if (blockIdx.x < 48)
        wsplit_body(Wq, Fqh, nullptr, 3 * CDIM, CDIM, blockIdx.x * 64 + ln, kq);
    else
        wsplit_body(Wp, Fph, Fpl, CDIM, CDIM, (blockIdx.x - 48) * 64 + ln, kq);
}

// ---------------------------------------------------------------------------
// 1-term MFMA GEMM with m97-style DMA-LDS staging (qkv), BK=64.
// (validated round 19)
// ---------------------------------------------------------------------------
__global__ __launch_bounds__(256) void gemm_lds1_kernel(
    const short* __restrict__ Ahf, const short* __restrict__ Bhf,
    const float* __restrict__ bias,
    uint* __restrict__ Cq, short* __restrict__ Ckf, short* __restrict__ Cvf,
    int M, int N, int K)
{
    __shared__ __align__(16) short Asm[8][2][64][8];   // 16 KB
    __shared__ __align__(16) short Bsm[8][2][64][8];   // 16 KB

    const int tid = threadIdx.x, lane = tid & 63, w = tid >> 6;
    const int wr = w >> 1, wc = w & 1, x = lane & 15, gl = lane >> 4;
    const int bm = blockIdx.y * 128, bn = blockIdx.x * 128;
    const int nkc = K >> 5;          // 32-wide chunks
    const int nks = K >> 6;          // 64-wide K-steps
    const size_t tstr = (size_t)nkc * 512;

    const short* sbase = (w < 2)
        ? Ahf + ((size_t)((bm >> 4) + 4 * w) * nkc) * 512 + (size_t)lane * 8
        : Bhf + ((size_t)((bn >> 4) + 4 * (w - 2)) * nkc) * 512 + (size_t)lane * 8;
    short* dbase = (w < 2) ? &Asm[4 * w][0][0][0] : &Bsm[4 * (w - 2)][0][0][0];

    f32x4 acc[4][4];
#pragma unroll
    for (int mi = 0; mi < 4; ++mi)
#pragma unroll
        for (int ni = 0; ni < 4; ++ni) acc[mi][ni] = (f32x4){0.f, 0.f, 0.f, 0.f};

    for (int kk = 0; kk < nks; ++kk) {
        __syncthreads();
#pragma unroll
        for (int i = 0; i < 4; ++i)
#pragma unroll
            for (int ch = 0; ch < 2; ++ch)
                gload_lds16(sbase + i * tstr + (size_t)(2 * kk + ch) * 512,
                            dbase + (i * 2 + ch) * 512);
        __syncthreads();

        bf16x8 ah[4][2], bh[4][2];
#pragma unroll
        for (int t = 0; t < 4; ++t)
#pragma unroll
            for (int ch = 0; ch < 2; ++ch) {
                ah[t][ch] = *(const bf16x8*)&Asm[wr * 4 + t][ch][lane][0];
                bh[t][ch] = *(const bf16x8*)&Bsm[wc * 4 + t][ch][lane][0];
            }
        __builtin_amdgcn_s_setprio(1);
#pragma unroll
        for (int mi = 0; mi < 4; ++mi)
#pragma unroll
            for (int ni = 0; ni < 4; ++ni) {
                acc[mi][ni] = __builtin_amdgcn_mfma_f32_16x16x32_bf16(ah[mi][0], bh[ni][0], acc[mi][ni], 0, 0, 0);
                acc[mi][ni] = __builtin_amdgcn_mfma_f32_16x16x32_bf16(ah[mi][1], bh[ni][1], acc[mi][ni], 0, 0, 0);
            }
        __builtin_amdgcn_s_setprio(0);
    }

    // ---- epilogue: qkv split ----
#pragma unroll
    for (int ni = 0; ni < 4; ++ni) {
        const int n = bn + wc * 64 + ni * 16 + x;
        const float bv = bias[n];
#pragma unroll
        for (int mi = 0; mi < 4; ++mi) {
            const int m0 = bm + wr * 64 + mi * 16 + gl * 4;
            const f32x4 o = acc[mi][ni];
            if (n < 1024) {
                Cq[(size_t)(m0 + 0) * 1024 + n] = packsplit((o[0] + bv) * QSCALE);
                Cq[(size_t)(m0 + 1) * 1024 + n] = packsplit((o[1] + bv) * QSCALE);
                Cq[(size_t)(m0 + 2) * 1024 + n] = packsplit((o[2] + bv) * QSCALE);
                Cq[(size_t)(m0 + 3) * 1024 + n] = packsplit((o[3] + bv) * QSCALE);
            } else if (n < 2048) {
                const int dd6 = n - 1024;
                const int hhh = dd6 >> 6, ch = (dd6 >> 5) & 1, dd = dd6 & 31;
                const int bq = m0 >> 11, sv = m0 & (T_SEQ - 1);
                const size_t base = ((((size_t)(bq * NHEAD + hhh) * 128 + (sv >> 4)) * 2 + ch) * 64
                                    + 16 * ((dd & 15) >> 2) + (sv & 15)) * 8
                                    + (dd & 3) + 4 * (dd >> 4);
                Ckf[base + 0]  = bfs(o[0] + bv);
                Ckf[base + 8]  = bfs(o[1] + bv);
                Ckf[base + 16] = bfs(o[2] + bv);
                Ckf[base + 24] = bfs(o[3] + bv);
            } else {
                const int dd6 = n - 2048;
                const int hhh = dd6 >> 6, dmi = (dd6 >> 4) & 3, xt = dd6 & 15;
                const int bq = m0 >> 11, sv = m0 & (T_SEQ - 1);
                const size_t base = ((((size_t)(bq * NHEAD + hhh) * 64 + (sv >> 5)) * 4 + dmi) * 64
                                    + xt + 16 * ((sv & 15) >> 2)) * 8 + 4 * ((sv >> 4) & 1);
                short4 st;
                st.x = bfs(o[0] + bv); st.y = bfs(o[1] + bv);
                st.z = bfs(o[2] + bv); st.w = bfs(o[3] + bv);
                *(short4*)&Cvf[base] = st;
            }
        }
    }
}

// ---------------------------------------------------------------------------
// MFMA GEMM, LDS-free, 2-D grid (3-term bf16x2 compensated; embed/proj/final).
// (validated round 17)
// ---------------------------------------------------------------------------
template <int TERMS>
__global__ __launch_bounds__(256) void gemm_mfma_kernel(
    const uint* __restrict__ Apf, const short* __restrict__ Ahf,
    const short* __restrict__ Bhf, const short* __restrict__ Blf,
    const float* __restrict__ bias, const float* __restrict__ addrow,
    uint* __restrict__ Cv, short* __restrict__ Chf,
    int M, int N, int K, int out_mode)
{
    const int tid = threadIdx.x, lane = tid & 63, w = tid >> 6;
    const int wr = w >> 1, wc = w & 1, x = lane & 15, gl = lane >> 4;
    const int bm = blockIdx.y * 128, bn = blockIdx.x * 128;
    const int nkc = K >> 5;

    const uint*  ab  = Apf ? Apf + ((size_t)((bm >> 4) + wr * 4) * nkc) * 512 + (size_t)lane * 8 : nullptr;
    const short* abh = Ahf ? Ahf + (((size_t)((bm >> 4) + wr * 4) * nkc) * 64 + lane) * 8 : nullptr;
    const short* hb  = Bhf + (((size_t)((bn >> 4) + wc * 4) * nkc) * 64 + lane) * 8;
    const short* lb  = Blf + (((size_t)((bn >> 4) + wc * 4) * nkc) * 64 + lane) * 8;
    const size_t tstrA = (size_t)nkc * 512;
    const size_t tstrF = (size_t)nkc * 512;

    f32x4 acc[4][4];
#pragma unroll
    for (int mi = 0; mi < 4; ++mi)
#pragma unroll
        for (int ni = 0; ni < 4; ++ni) acc[mi][ni] = (f32x4){0.f, 0.f, 0.f, 0.f};

    for (int kc = 0; kc < nkc; ++kc) {
        const size_t ko = (size_t)kc * 512;
        bf16x8 ah[4], al[4], bh[4], bl[4];
#pragma unroll
        for (int t = 0; t < 4; ++t) {
            if (TERMS == 1) {
                ah[t] = *(const bf16x8*)(abh + t * tstrF + ko);
            } else {
                const uint* ap = ab + t * tstrA + ko;
                uint4 a0 = *(const uint4*)ap;
                uint4 a1 = *(const uint4*)(ap + 4);
                i32x4 h4, l4;
                h4[0] = (int)prm(a0.y, a0.x, SELHI); h4[1] = (int)prm(a0.w, a0.z, SELHI);
                h4[2] = (int)prm(a1.y, a1.x, SELHI); h4[3] = (int)prm(a1.w, a1.z, SELHI);
                l4[0] = (int)prm(a0.y, a0.x, SELLO); l4[1] = (int)prm(a0.w, a0.z, SELLO);
                l4[2] = (int)prm(a1.y, a1.x, SELLO); l4[3] = (int)prm(a1.w, a1.z, SELLO);
                ah[t] = asb(h4); al[t] = asb(l4);
            }
            bh[t] = *(const bf16x8*)(hb + t * tstrF + ko);
            if (TERMS >= 3) bl[t] = *(const bf16x8*)(lb + t * tstrF + ko);
        }
        __builtin_amdgcn_s_setprio(1);
#pragma unroll
        for (int mi = 0; mi < 4; ++mi)
#pragma unroll
            for (int ni = 0; ni < 4; ++ni) {
                acc[mi][ni] = __builtin_amdgcn_mfma_f32_16x16x32_bf16(ah[mi], bh[ni], acc[mi][ni], 0, 0, 0);
                if (TERMS >= 3)
                    acc[mi][ni] = __builtin_amdgcn_mfma_f32_16x16x32_bf16(ah[mi], bl[ni], acc[mi][ni], 0, 0, 0);
                if (TERMS >= 2)
                    acc[mi][ni] = __builtin_amdgcn_mfma_f32_16x16x32_bf16(al[mi], bh[ni], acc[mi][ni], 0, 0, 0);
            }
        __builtin_amdgcn_s_setprio(0);
    }

#pragma unroll
    for (int ni = 0; ni < 4; ++ni) {
        const int n = bn + wc * 64 + ni * 16 + x;
        const float bv = bias[n];
#pragma unroll
        for (int mi = 0; mi < 4; ++mi) {
            const int m0 = bm + wr * 64 + mi * 16 + gl * 4;
            const f32x4 o = acc[mi][ni];
            if (out_mode == 0) {
                float* C = (float*)Cv;
                C[(size_t)(m0 + 0) * N + n] = o[0] + bv;
                C[(size_t)(m0 + 1) * N + n] = o[1] + bv;
                C[(size_t)(m0 + 2) * N + n] = o[2] + bv;
                C[(size_t)(m0 + 3) * N + n] = o[3] + bv;
            } else {
                float p0 = 0.f, p1 = 0.f, p2 = 0.f, p3 = 0.f;
                if (addrow) {
                    p0 = addrow[(size_t)((m0 + 0) & (T_SEQ - 1)) * N + n];
                    p1 = addrow[(size_t)((m0 + 1) & (T_SEQ - 1)) * N + n];
                    p2 = addrow[(size_t)((m0 + 2) & (T_SEQ - 1)) * N + n];
                    p3 = addrow[(size_t)((m0 + 3) & (T_SEQ - 1)) * N + n];
                }
                const float v0 = o[0] + bv + p0, v1 = o[1] + bv + p1;
                const float v2 = o[2] + bv + p2, v3 = o[3] + bv + p3;
                const size_t mt = (size_t)(bm >> 4) + wr * 4 + mi;
                const size_t base = (mt * (N >> 5) + (n >> 5)) * 512
                                  + (size_t)(((n >> 2) & 3) * 16 + gl * 4) * 8
                                  + (n & 3) + 4 * ((n >> 4) & 1);
                Cv[base + 0 * 8] = packsplit(v0);
                Cv[base + 1 * 8] = packsplit(v1);
                Cv[base + 2 * 8] = packsplit(v2);
                Cv[base + 3 * 8] = packsplit(v3);
                if (Chf) {
                    const size_t fb = ((mt * (N >> 5) + (n >> 5)) * 64
                                      + ((n >> 2) & 3) * 16 + gl * 4) * 8
                                      + (n & 3) + 4 * ((n >> 4) & 1);
                    Chf[fb + 0 * 8] = bfs(v0);
                    Chf[fb + 1 * 8] = bfs(v1);
                    Chf[fb + 2 * 8] = bfs(v2);
                    Chf[fb + 3 * 8] = bfs(v3);
                }
            }
        }
    }
}

// ---------------------------------------------------------------------------
// Flash attention with LDS-broadcast K/V frags. QBLK=128, 4 waves x 2 q-frags.
// Per 64-s tile: each wave DMAs 4 of the 16 pre-formed K/V frags into LDS
// (pure global_load_lds, no repacking), barrier, all waves ds_read_b128 them
// -> intra-block L2 read redundancy 4x -> 1x. Compute identical to round 19:
// QK 1-term + exp2, PV 1-term, l via ones-MFMA. XCD-swizzled.
// ---------------------------------------------------------------------------
__global__ __launch_bounds__(256) void attn_mfma_kernel(
    const uint* __restrict__ qrow, const short* __restrict__ kf,
    const short* __restrict__ vf, uint* __restrict__ y)
{
    __shared__ __align__(16) short fr[16][512];   // 16 KB: 0-7 K(sc*2+ch), 8-15 V(ch*4+dm)

    const int tid  = threadIdx.x;
    const int w    = tid >> 6;
    const int lane = tid & 63;
    const int x    = lane & 15;
    const int gl   = lane >> 4;

    const int orig = blockIdx.x;
    const int wgid = (orig & 7) * 64 + (orig >> 3);
    const int bh = wgid >> 4;
    const int b = bh >> 4, hh = bh & 15;
    const int t0 = (wgid & 15) * 128;

    i32x4 qhi[2][2];
#pragma unroll
    for (int qf = 0; qf < 2; ++qf) {
        const uint* qp = qrow + (size_t)(b * T_SEQ + t0 + 64 * qf + 16 * w + x) * 1024 + hh * 64;
#pragma unroll
        for (int ch = 0; ch < 2; ++ch) {
            uint4 a0 = *(const uint4*)(qp + 32 * ch + 4 * gl);
            uint4 a1 = *(const uint4*)(qp + 32 * ch + 16 + 4 * gl);
            qhi[qf][ch][0] = (int)prm(a0.y, a0.x, SELHI); qhi[qf][ch][1] = (int)prm(a0.w, a0.z, SELHI);
            qhi[qf][ch][2] = (int)prm(a1.y, a1.x, SELHI); qhi[qf][ch][3] = (int)prm(a1.w, a1.z, SELHI);
        }
    }

    // DMA source for this wave's 4 frags. K frag f (=sc*2+ch) of tile t lives at
    // kf + (bh*256 + 8t + f)*512; V frag g (=ch*4+dm) at vf + (bh*256 + 8t + g)*512.
    // Wave 0: K f=0..3, wave 1: K f=4..7, wave 2: V g=0..3, wave 3: V g=4..7.
    const short* sb = (w < 2)
        ? kf + ((size_t)bh * 256 + 4 * w) * 512 + (size_t)lane * 8
        : vf + ((size_t)bh * 256 + 4 * (w - 2)) * 512 + (size_t)lane * 8;
    short* db = &fr[4 * w][0];

    i32x4 ones4;
    ones4[0] = ones4[1] = ones4[2] = ones4[3] = 0x3F803F80;  // 8x bf16 1.0

    f32x4 oacc[2][4], lacc[2];
#pragma unroll
    for (int qf = 0; qf < 2; ++qf) {
        lacc[qf] = (f32x4){0.f, 0.f, 0.f, 0.f};
#pragma unroll
        for (int i = 0; i < 4; ++i) oacc[qf][i] = (f32x4){0.f, 0.f, 0.f, 0.f};
    }

    for (int t = 0; t < T_SEQ / 64; ++t) {
        __syncthreads();   // previous tile's ds_reads complete before overwrite
#pragma unroll
        for (int i = 0; i < 4; ++i)
            gload_lds16(sb + ((size_t)8 * t + i) * 512, db + i * 512);
        __syncthreads();   // DMA drained; frags visible to all waves

        bf16x8 kh[4][2], vh[2][4];
#pragma unroll
        for (int sc = 0; sc < 4; ++sc)
#pragma unroll
            for (int ch = 0; ch < 2; ++ch)
                kh[sc][ch] = *(const bf16x8*)&fr[sc * 2 + ch][lane * 8];
#pragma unroll
        for (int ch = 0; ch < 2; ++ch)
#pragma unroll
            for (int dm = 0; dm < 4; ++dm)
                vh[ch][dm] = *(const bf16x8*)&fr[8 + ch * 4 + dm][lane * 8];

#pragma unroll
        for (int qf = 0; qf < 2; ++qf) {
            f32x4 s4[4];
#pragma unroll
            for (int sc = 0; sc < 4; ++sc) {
                s4[sc] = (f32x4){0.f, 0.f, 0.f, 0.f};
                s4[sc] = __builtin_amdgcn_mfma_f32_16x16x32_bf16(kh[sc][0], asb(qhi[qf][0]), s4[sc], 0, 0, 0);
                s4[sc] = __builtin_amdgcn_mfma_f32_16x16x32_bf16(kh[sc][1], asb(qhi[qf][1]), s4[sc], 0, 0, 0);
            }
#pragma unroll
            for (int sc = 0; sc < 4; ++sc) {
                s4[sc][0] = __builtin_amdgcn_exp2f(s4[sc][0]);
                s4[sc][1] = __builtin_amdgcn_exp2f(s4[sc][1]);
                s4[sc][2] = __builtin_amdgcn_exp2f(s4[sc][2]);
                s4[sc][3] = __builtin_amdgcn_exp2f(s4[sc][3]);
            }
            i32x4 pfh[2];
#pragma unroll
            for (int c = 0; c < 2; ++c) {
                f32x4 pa = s4[2 * c], pb = s4[2 * c + 1];
                pfh[c][0] = (int)prm(__float_as_uint(pa[1]), __float_as_uint(pa[0]), SELHI);
                pfh[c][1] = (int)prm(__float_as_uint(pa[3]), __float_as_uint(pa[2]), SELHI);
                pfh[c][2] = (int)prm(__float_as_uint(pb[1]), __float_as_uint(pb[0]), SELHI);
                pfh[c][3] = (int)prm(__float_as_uint(pb[3]), __float_as_uint(pb[2]), SELHI);
            }
            lacc[qf] = __builtin_amdgcn_mfma_f32_16x16x32_bf16(asb(ones4), asb(pfh[0]), lacc[qf], 0, 0, 0);
            lacc[qf] = __builtin_amdgcn_mfma_f32_16x16x32_bf16(asb(ones4), asb(pfh[1]), lacc[qf], 0, 0, 0);
#pragma unroll
            for (int dm = 0; dm < 4; ++dm) {
                oacc[qf][dm] = __builtin_amdgcn_mfma_f32_16x16x32_bf16(vh[0][dm], asb(pfh[0]), oacc[qf][dm], 0, 0, 0);
                oacc[qf][dm] = __builtin_amdgcn_mfma_f32_16x16x32_bf16(vh[1][dm], asb(pfh[1]), oacc[qf][dm], 0, 0, 0);
            }
        }
    }

#pragma unroll
    for (int qf = 0; qf < 2; ++qf) {
        const float invl = 1.f / lacc[qf][0];
        const size_t mt = (size_t)((b * T_SEQ + t0) >> 4) + 4 * qf + w;
#pragma unroll
        for (int dm = 0; dm < 4; ++dm) {
            f32x4 o = oacc[qf][dm];
            const size_t addr = (mt * 32 + hh * 2 + (dm >> 1)) * 512
                              + (size_t)lane * 8 + 4 * (dm & 1);
            uint4 pk;
            pk.x = packsplit(o[0] * invl); pk.y = packsplit(o[1] * invl);
            pk.z = packsplit(o[2] * invl); pk.w = packsplit(o[3] * invl);
            *(uint4*)&y[addr] = pk;
        }
    }
}

// ---------------------------------------------------------------------------
// LayerNorm; input frag-packed u32, output frag-packed u32 (for MFMA out GEMM).
// ---------------------------------------------------------------------------
__global__ __launch_bounds__(256) void ln_kernel(
    const uint* __restrict__ h, const float* __restrict__ gamma,
    const float* __restrict__ beta, uint* __restrict__ outp)
{
    const int row = blockIdx.x;
    const int tid = threadIdx.x;

    const size_t addr = ((size_t)(row >> 4) * 32 + (tid >> 3)) * 512
                      + (size_t)((tid & 3) * 16 + (row & 15)) * 8
                      + 4 * ((tid >> 2) & 1);
    uint4 u = *(const uint4*)&h[addr];
    float4 v;
    v.x = unpack2(u.x); v.y = unpack2(u.y); v.z = unpack2(u.z); v.w = unpack2(u.w);

    float s  = v.x + v.y + v.z + v.w;
    float ss = v.x * v.x + v.y * v.y + v.z * v.z + v.w * v.w;
#pragma unroll
    for (int off = 1; off < 64; off <<= 1) {
        s  += __shfl_xor(s, off);
        ss += __shfl_xor(ss, off);
    }
    __shared__ float rs[4], rss[4];
    const int wid = tid >> 6;
    if ((tid & 63) == 0) { rs[wid] = s; rss[wid] = ss; }
    __syncthreads();
    s  = rs[0] + rs[1] + rs[2] + rs[3];
    ss = rss[0] + rss[1] + rss[2] + rss[3];

    const float mu   = s * (1.f / (float)CDIM);
    const float var  = ss * (1.f / (float)CDIM) - mu * mu;
    const float rstd = rsqrtf(var + 1e-5f);

    const float4 g  = *(const float4*)&gamma[tid * 4];
    const float4 be = *(const float4*)&beta[tid * 4];
    uint4 pk;
    pk.x = packsplit((v.x - mu) * rstd * g.x + be.x);
    pk.y = packsplit((v.y - mu) * rstd * g.y + be.y);
    pk.z = packsplit((v.z - mu) * rstd * g.z + be.z);
    pk.w = packsplit((v.w - mu) * rstd * g.w + be.w);
    *(uint4*)&outp[addr] = pk;   // same frag-packed layout as input
}

// ---------------------------------------------------------------------------
extern "C" void kernel_launch(void* const* d_in, const int* in_sizes, int n_in,
                              void* d_out, int out_size, void* d_ws, size_t ws_size,
                              hipStream_t stream)
{
    const float* x      = (const float*)d_in[0];
    const float* W_emb  = (const float*)d_in[1];
    const float* b_emb  = (const float*)d_in[2];
    const float* pos    = (const float*)d_in[3];
    const float* Wqkv   = (const float*)d_in[4];
    const float* bqkv   = (const float*)d_in[5];
    const float* Wproj  = (const float*)d_in[6];
    const float* bproj  = (const float*)d_in[7];
    const float* gamma  = (const float*)d_in[8];
    const float* beta   = (const float*)d_in[9];
    const float* W_out  = (const float*)d_in[10];
    const float* b_out  = (const float*)d_in[11];
    float* out = (float*)d_out;

    uint* h    = (uint*)d_ws;                       // [4096][1024] frag-packed
    uint* qrow = h + (size_t)MROWS * CDIM;          // Q row-major packed; reused as LN output
    uint* y    = qrow + (size_t)MROWS * CDIM;       // [4096][1024] frag-packed (attn out)
    short* kf  = (short*)(y + (size_t)MROWS * CDIM);            // 32*128*2*512 bf16
    short* vfb = kf + (size_t)32 * 128 * 2 * 512;               // 32*64*4*512 bf16
    short* hf  = vfb + (size_t)32 * 64 * 4 * 512;   // h hi-only bf16 frags (4096x1024)
    short* Bqh = hf + (size_t)MROWS * CDIM;
    short* Bph = Bqh + (size_t)3 * CDIM * CDIM;
    short* Bpl = Bph + (size_t)CDIM * CDIM;
    short* Eh  = Bpl + (size_t)CDIM * CDIM;         // W_emb hi  (256x1024)
    short* El  = Eh  + (size_t)VDIM * CDIM;         // W_emb lo
    short* Oh  = El  + (size_t)VDIM * CDIM;         // W_out hi  (1024x256)
    short* Ol  = Oh  + (size_t)CDIM * VDIM;         // W_out lo
    uint*  xpf = (uint*)(Ol + (size_t)CDIM * VDIM); // x frag-packed (4096x256)

    const dim3 blk(256);
    const int nattn = (T_SEQ / 128) * BATCH * NHEAD;  // 512 blocks, 1-D swizzled

    // ---- embed: h(frag + hi-frag) = x @ W_emb + b_emb + pos, via MFMA ----
    packx_kernel<<<dim3(MROWS * (VDIM / 4) / 256), blk, 0, stream>>>(x, xpf);
    wsplit_kernel<<<dim3(CDIM / 64, VDIM / 16), blk, 0, stream>>>(W_emb, Eh, El, CDIM, VDIM);
    gemm_mfma_kernel<3><<<dim3(CDIM / 128, MROWS / 128), blk, 0, stream>>>(
        xpf, nullptr, Eh, El, b_emb, pos, h, hf, MROWS, CDIM, VDIM, 2);

    for (int l = 0; l < NLAYER; ++l) {
        wsplit2_kernel<<<dim3(64, CDIM / 16), blk, 0, stream>>>(
            Wqkv + (size_t)l * CDIM * 3 * CDIM, Bqh,
            Wproj + (size_t)l * CDIM * CDIM, Bph, Bpl);
        gemm_lds1_kernel<<<dim3(3 * CDIM / 128, MROWS / 128), blk, 0, stream>>>(
            hf, Bqh, bqkv + (size_t)l * 3 * CDIM, qrow, kf, vfb, MROWS, 3 * CDIM, CDIM);
        attn_mfma_kernel<<<dim3(nattn), blk, 0, stream>>>(qrow, kf, vfb, y);
        gemm_mfma_kernel<3><<<dim3(CDIM / 128, MROWS / 128), blk, 0, stream>>>(
            y, nullptr, Bph, Bpl, bproj + (size_t)l * CDIM, nullptr,
            h, hf, MROWS, CDIM, CDIM, 2);
    }

    // ---- LN (frag->frag, into qrow) + final out GEMM via MFMA ----
    ln_kernel<<<dim3(MROWS), blk, 0, stream>>>(h, gamma, beta, qrow);
    wsplit_kernel<<<dim3(VDIM / 64, CDIM / 16), blk, 0, stream>>>(W_out, Oh, Ol, VDIM, CDIM);
    gemm_mfma_kernel<3><<<dim3(VDIM / 128, MROWS / 128), blk, 0, stream>>>(
        qrow, nullptr, Oh, Ol, b_out, nullptr, (uint*)out, nullptr, MROWS, VDIM, CDIM, 0);
}

// Round 21
// 1020.455 us; speedup vs baseline: 1.0512x; 1.0512x over previous
//
#include <hip/hip_runtime.h>
#include <hip/hip_bf16.h>

#define T_SEQ 2048
#define BATCH 2
#define CDIM 1024
#define VDIM 256
#define NHEAD 16
#define DHEAD 64
#define NLAYER 8
#define MROWS (BATCH * T_SEQ) /* 4096 */

typedef __attribute__((ext_vector_type(8))) short bf16x8;
typedef __attribute__((ext_vector_type(4))) float f32x4;
typedef __attribute__((ext_vector_type(4))) int i32x4;

#define SELHI 0x07060302u
#define SELLO 0x05040100u
#define QSCALE 0.18033688011112042f  /* 0.125 * log2(e) */

__device__ __forceinline__ uint prm(uint a, uint b, uint s) { return __builtin_amdgcn_perm(a, b, s); }

__device__ __forceinline__ uint bf16rne(float f) {
    uint u = __float_as_uint(f);
    return (u + 0x7fffu + ((u >> 16) & 1u)) & 0xffff0000u;
}
__device__ __forceinline__ uint packsplit(float x) {
    uint hb = bf16rne(x);
    float d = x - __uint_as_float(hb);
    uint lb = bf16rne(d);
    return prm(hb, lb, SELHI);
}
__device__ __forceinline__ float unpack2(uint u) {
    return __uint_as_float(u & 0xffff0000u) + __uint_as_float(u << 16);
}
__device__ __forceinline__ bf16x8 asb(i32x4 v) {
    union { i32x4 i; bf16x8 b; } u; u.i = v; return u.b;
}
__device__ __forceinline__ short bfs(float f) { return (short)(bf16rne(f) >> 16); }
// async global->LDS DMA, 16B per lane: lds slot = uniform base + lane*16
__device__ __forceinline__ void gload_lds16(const void* g, void* l) {
    __builtin_amdgcn_global_load_lds(
        (const __attribute__((address_space(1))) void*)g,
        (__attribute__((address_space(3))) void*)l, 16, 0, 0);
}

// Frag-packed u32 activation layout for X[M][K] (K mult of 32):
//   slot(m,k) = ((m>>4)*(K>>5)+(k>>5))*512 + (((k>>2)&3)*16+(m&15))*8 + (k&3)+4*((k>>4)&1)
// Hi-only bf16 frag layout (A-operand direct):
//   slot(m,k) = (((m>>4)*(K>>5)+(k>>5))*64 + ((k>>2)&3)*16 + (m&15))*8 + (k&3)+4*((k>>4)&1)

// ---------------------------------------------------------------------------
// Pack x (f32 rows, K=256) -> frag-packed hi|lo u32.
// ---------------------------------------------------------------------------
__global__ __launch_bounds__(256) void packx_kernel(
    const float* __restrict__ x, uint* __restrict__ xpf)
{
    const int t  = blockIdx.x * 256 + threadIdx.x;   // 0 .. 4096*64-1
    const int m  = t >> 6;
    const int k0 = (t & 63) * 4;
    const float4 v = *(const float4*)&x[(size_t)m * 256 + k0];
    const size_t addr = ((size_t)(m >> 4) * 8 + (k0 >> 5)) * 512
                      + (size_t)(((k0 >> 2) & 3) * 16 + (m & 15)) * 8
                      + 4 * ((k0 >> 4) & 1);
    uint4 pk;
    pk.x = packsplit(v.x); pk.y = packsplit(v.y);
    pk.z = packsplit(v.z); pk.w = packsplit(v.w);
    *(uint4*)&xpf[addr] = pk;
}

// ---------------------------------------------------------------------------
// Weight pre-split: W[K][N] f32 -> frag-order hi (and optionally lo) bf16.
// ---------------------------------------------------------------------------
__device__ __forceinline__ void wsplit_body(
    const float* __restrict__ W, short* __restrict__ Fh, short* __restrict__ Fl,
    int N, int K, int n, int kq)
{
    const int k0 = kq * 4;
    float f0 = W[(size_t)(k0 + 0) * N + n];
    float f1 = W[(size_t)(k0 + 1) * N + n];
    float f2 = W[(size_t)(k0 + 2) * N + n];
    float f3 = W[(size_t)(k0 + 3) * N + n];
    uint h0 = bf16rne(f0), h1 = bf16rne(f1), h2 = bf16rne(f2), h3 = bf16rne(f3);

    const int gl = kq & 3, j0 = ((kq >> 2) & 1) * 4;
    const size_t base = (((size_t)(n >> 4) * (K >> 5) + (kq >> 3)) * 64 + gl * 16 + (n & 15)) * 8 + j0;
    *(int2*)&Fh[base] = make_int2((int)prm(h1, h0, SELHI), (int)prm(h3, h2, SELHI));
    if (Fl) {
        uint l0 = bf16rne(f0 - __uint_as_float(h0));
        uint l1 = bf16rne(f1 - __uint_as_float(h1));
        uint l2 = bf16rne(f2 - __uint_as_float(h2));
        uint l3 = bf16rne(f3 - __uint_as_float(h3));
        *(int2*)&Fl[base] = make_int2((int)prm(l1, l0, SELHI), (int)prm(l3, l2, SELHI));
    }
}

__global__ __launch_bounds__(256) void wsplit_kernel(
    const float* __restrict__ W, short* __restrict__ Fh, short* __restrict__ Fl,
    int N, int K)
{
    const int ln = threadIdx.x & 63, lk = threadIdx.x >> 6;
    wsplit_body(W, Fh, Fl, N, K, blockIdx.x * 64 + ln, blockIdx.y * 4 + lk);
}

// Fused per-layer split: Wqkv (hi only, N=3072) + Wproj (hi+lo, N=1024), K=1024.
__global__ __launch_bounds__(256) void wsplit2_kernel(
    const float* __restrict__ Wq, short* __restrict__ Fqh,
    const float* __restrict__ Wp, short* __restrict__ Fph, short* __restrict__ Fpl)
{
    const int ln = threadIdx.x & 63, lk = threadIdx.x >> 6;
    const int kq = blockIdx.y * 4 + lk;
    if (blockIdx.x < 48)
        wsplit_body(Wq, Fqh, nullptr, 3 * CDIM, CDIM, blockIdx.x * 64 + ln, kq);
    else
        wsplit_body(Wp, Fph, Fpl, CDIM, CDIM, (blockIdx.x - 48) * 64 + ln, kq);
}

// ---------------------------------------------------------------------------
// 1-term MFMA GEMM with m97-style DMA-LDS staging (qkv), BK=64.
// (validated round 19)
// ---------------------------------------------------------------------------
__global__ __launch_bounds__(256) void gemm_lds1_kernel(
    const short* __restrict__ Ahf, const short* __restrict__ Bhf,
    const float* __restrict__ bias,
    uint* __restrict__ Cq, short* __restrict__ Ckf, short* __restrict__ Cvf,
    int M, int N, int K)
{
    __shared__ __align__(16) short Asm[8][2][64][8];   // 16 KB
    __shared__ __align__(16) short Bsm[8][2][64][8];   // 16 KB

    const int tid = threadIdx.x, lane = tid & 63, w = tid >> 6;
    const int wr = w >> 1, wc = w & 1, x = lane & 15, gl = lane >> 4;
    const int bm = blockIdx.y * 128, bn = blockIdx.x * 128;
    const int nkc = K >> 5;          // 32-wide chunks
    const int nks = K >> 6;          // 64-wide K-steps
    const size_t tstr = (size_t)nkc * 512;

    const short* sbase = (w < 2)
        ? Ahf + ((size_t)((bm >> 4) + 4 * w) * nkc) * 512 + (size_t)lane * 8
        : Bhf + ((size_t)((bn >> 4) + 4 * (w - 2)) * nkc) * 512 + (size_t)lane * 8;
    short* dbase = (w < 2) ? &Asm[4 * w][0][0][0] : &Bsm[4 * (w - 2)][0][0][0];

    f32x4 acc[4][4];
#pragma unroll
    for (int mi = 0; mi < 4; ++mi)
#pragma unroll
        for (int ni = 0; ni < 4; ++ni) acc[mi][ni] = (f32x4){0.f, 0.f, 0.f, 0.f};

    for (int kk = 0; kk < nks; ++kk) {
        __syncthreads();
#pragma unroll
        for (int i = 0; i < 4; ++i)
#pragma unroll
            for (int ch = 0; ch < 2; ++ch)
                gload_lds16(sbase + i * tstr + (size_t)(2 * kk + ch) * 512,
                            dbase + (i * 2 + ch) * 512);
        __syncthreads();

        bf16x8 ah[4][2], bh[4][2];
#pragma unroll
        for (int t = 0; t < 4; ++t)
#pragma unroll
            for (int ch = 0; ch < 2; ++ch) {
                ah[t][ch] = *(const bf16x8*)&Asm[wr * 4 + t][ch][lane][0];
                bh[t][ch] = *(const bf16x8*)&Bsm[wc * 4 + t][ch][lane][0];
            }
        __builtin_amdgcn_s_setprio(1);
#pragma unroll
        for (int mi = 0; mi < 4; ++mi)
#pragma unroll
            for (int ni = 0; ni < 4; ++ni) {
                acc[mi][ni] = __builtin_amdgcn_mfma_f32_16x16x32_bf16(ah[mi][0], bh[ni][0], acc[mi][ni], 0, 0, 0);
                acc[mi][ni] = __builtin_amdgcn_mfma_f32_16x16x32_bf16(ah[mi][1], bh[ni][1], acc[mi][ni], 0, 0, 0);
            }
        __builtin_amdgcn_s_setprio(0);
    }

    // ---- epilogue: qkv split ----
#pragma unroll
    for (int ni = 0; ni < 4; ++ni) {
        const int n = bn + wc * 64 + ni * 16 + x;
        const float bv = bias[n];
#pragma unroll
        for (int mi = 0; mi < 4; ++mi) {
            const int m0 = bm + wr * 64 + mi * 16 + gl * 4;
            const f32x4 o = acc[mi][ni];
            if (n < 1024) {
                Cq[(size_t)(m0 + 0) * 1024 + n] = packsplit((o[0] + bv) * QSCALE);
                Cq[(size_t)(m0 + 1) * 1024 + n] = packsplit((o[1] + bv) * QSCALE);
                Cq[(size_t)(m0 + 2) * 1024 + n] = packsplit((o[2] + bv) * QSCALE);
                Cq[(size_t)(m0 + 3) * 1024 + n] = packsplit((o[3] + bv) * QSCALE);
            } else if (n < 2048) {
                const int dd6 = n - 1024;
                const int hhh = dd6 >> 6, ch = (dd6 >> 5) & 1, dd = dd6 & 31;
                const int bq = m0 >> 11, sv = m0 & (T_SEQ - 1);
                const size_t base = ((((size_t)(bq * NHEAD + hhh) * 128 + (sv >> 4)) * 2 + ch) * 64
                                    + 16 * ((dd & 15) >> 2) + (sv & 15)) * 8
                                    + (dd & 3) + 4 * (dd >> 4);
                Ckf[base + 0]  = bfs(o[0] + bv);
                Ckf[base + 8]  = bfs(o[1] + bv);
                Ckf[base + 16] = bfs(o[2] + bv);
                Ckf[base + 24] = bfs(o[3] + bv);
            } else {
                const int dd6 = n - 2048;
                const int hhh = dd6 >> 6, dmi = (dd6 >> 4) & 3, xt = dd6 & 15;
                const int bq = m0 >> 11, sv = m0 & (T_SEQ - 1);
                const size_t base = ((((size_t)(bq * NHEAD + hhh) * 64 + (sv >> 5)) * 4 + dmi) * 64
                                    + xt + 16 * ((sv & 15) >> 2)) * 8 + 4 * ((sv >> 4) & 1);
                short4 st;
                st.x = bfs(o[0] + bv); st.y = bfs(o[1] + bv);
                st.z = bfs(o[2] + bv); st.w = bfs(o[3] + bv);
                *(short4*)&Cvf[base] = st;
            }
        }
    }
}

// ---------------------------------------------------------------------------
// MFMA GEMM, LDS-free, 2-D grid. TERMS = 1 or 3; NI = n-frags per wave
// (tile N = 32*NI): embed NI=4 (256 blk), proj NI=2 (512 blk, 2 blk/CU),
// final NI=1 (256 blk). Accumulation order unchanged -> bit-identical.
// out_mode 0: f32 rows. out_mode 2: frag-packed u32 Cv (+addrow) + opt Chf.
// ---------------------------------------------------------------------------
template <int TERMS, int NI>
__global__ __launch_bounds__(256) void gemm_mfma_kernel(
    const uint* __restrict__ Apf, const short* __restrict__ Ahf,
    const short* __restrict__ Bhf, const short* __restrict__ Blf,
    const float* __restrict__ bias, const float* __restrict__ addrow,
    uint* __restrict__ Cv, short* __restrict__ Chf,
    int M, int N, int K, int out_mode)
{
    const int tid = threadIdx.x, lane = tid & 63, w = tid >> 6;
    const int wr = w >> 1, wc = w & 1, x = lane & 15, gl = lane >> 4;
    const int bm = blockIdx.y * 128, bn = blockIdx.x * (32 * NI);
    const int nkc = K >> 5;

    const uint*  ab  = Apf ? Apf + ((size_t)((bm >> 4) + wr * 4) * nkc) * 512 + (size_t)lane * 8 : nullptr;
    const short* abh = Ahf ? Ahf + (((size_t)((bm >> 4) + wr * 4) * nkc) * 64 + lane) * 8 : nullptr;
    const short* hb  = Bhf + (((size_t)((bn >> 4) + wc * NI) * nkc) * 64 + lane) * 8;
    const short* lb  = Blf + (((size_t)((bn >> 4) + wc * NI) * nkc) * 64 + lane) * 8;
    const size_t tstrA = (size_t)nkc * 512;
    const size_t tstrF = (size_t)nkc * 512;

    f32x4 acc[4][NI];
#pragma unroll
    for (int mi = 0; mi < 4; ++mi)
#pragma unroll
        for (int ni = 0; ni < NI; ++ni) acc[mi][ni] = (f32x4){0.f, 0.f, 0.f, 0.f};

    for (int kc = 0; kc < nkc; ++kc) {
        const size_t ko = (size_t)kc * 512;
        bf16x8 ah[4], al[4], bh[NI], bl[NI];
#pragma unroll
        for (int t = 0; t < 4; ++t) {
            if (TERMS == 1) {
                ah[t] = *(const bf16x8*)(abh + t * tstrF + ko);
            } else {
                const uint* ap = ab + t * tstrA + ko;
                uint4 a0 = *(const uint4*)ap;
                uint4 a1 = *(const uint4*)(ap + 4);
                i32x4 h4, l4;
                h4[0] = (int)prm(a0.y, a0.x, SELHI); h4[1] = (int)prm(a0.w, a0.z, SELHI);
                h4[2] = (int)prm(a1.y, a1.x, SELHI); h4[3] = (int)prm(a1.w, a1.z, SELHI);
                l4[0] = (int)prm(a0.y, a0.x, SELLO); l4[1] = (int)prm(a0.w, a0.z, SELLO);
                l4[2] = (int)prm(a1.y, a1.x, SELLO); l4[3] = (int)prm(a1.w, a1.z, SELLO);
                ah[t] = asb(h4); al[t] = asb(l4);
            }
        }
#pragma unroll
        for (int t = 0; t < NI; ++t) {
            bh[t] = *(const bf16x8*)(hb + t * tstrF + ko);
            if (TERMS >= 3) bl[t] = *(const bf16x8*)(lb + t * tstrF + ko);
        }
        __builtin_amdgcn_s_setprio(1);
#pragma unroll
        for (int mi = 0; mi < 4; ++mi)
#pragma unroll
            for (int ni = 0; ni < NI; ++ni) {
                acc[mi][ni] = __builtin_amdgcn_mfma_f32_16x16x32_bf16(ah[mi], bh[ni], acc[mi][ni], 0, 0, 0);
                if (TERMS >= 3)
                    acc[mi][ni] = __builtin_amdgcn_mfma_f32_16x16x32_bf16(ah[mi], bl[ni], acc[mi][ni], 0, 0, 0);
                if (TERMS >= 2)
                    acc[mi][ni] = __builtin_amdgcn_mfma_f32_16x16x32_bf16(al[mi], bh[ni], acc[mi][ni], 0, 0, 0);
            }
        __builtin_amdgcn_s_setprio(0);
    }

#pragma unroll
    for (int ni = 0; ni < NI; ++ni) {
        const int n = bn + wc * (16 * NI) + ni * 16 + x;
        const float bv = bias[n];
#pragma unroll
        for (int mi = 0; mi < 4; ++mi) {
            const int m0 = bm + wr * 64 + mi * 16 + gl * 4;
            const f32x4 o = acc[mi][ni];
            if (out_mode == 0) {
                float* C = (float*)Cv;
                C[(size_t)(m0 + 0) * N + n] = o[0] + bv;
                C[(size_t)(m0 + 1) * N + n] = o[1] + bv;
                C[(size_t)(m0 + 2) * N + n] = o[2] + bv;
                C[(size_t)(m0 + 3) * N + n] = o[3] + bv;
            } else {
                float p0 = 0.f, p1 = 0.f, p2 = 0.f, p3 = 0.f;
                if (addrow) {
                    p0 = addrow[(size_t)((m0 + 0) & (T_SEQ - 1)) * N + n];
                    p1 = addrow[(size_t)((m0 + 1) & (T_SEQ - 1)) * N + n];
                    p2 = addrow[(size_t)((m0 + 2) & (T_SEQ - 1)) * N + n];
                    p3 = addrow[(size_t)((m0 + 3) & (T_SEQ - 1)) * N + n];
                }
                const float v0 = o[0] + bv + p0, v1 = o[1] + bv + p1;
                const float v2 = o[2] + bv + p2, v3 = o[3] + bv + p3;
                const size_t mt = (size_t)(bm >> 4) + wr * 4 + mi;
                const size_t base = (mt * (N >> 5) + (n >> 5)) * 512
                                  + (size_t)(((n >> 2) & 3) * 16 + gl * 4) * 8
                                  + (n & 3) + 4 * ((n >> 4) & 1);
                Cv[base + 0 * 8] = packsplit(v0);
                Cv[base + 1 * 8] = packsplit(v1);
                Cv[base + 2 * 8] = packsplit(v2);
                Cv[base + 3 * 8] = packsplit(v3);
                if (Chf) {
                    const size_t fb = ((mt * (N >> 5) + (n >> 5)) * 64
                                      + ((n >> 2) & 3) * 16 + gl * 4) * 8
                                      + (n & 3) + 4 * ((n >> 4) & 1);
                    Chf[fb + 0 * 8] = bfs(v0);
                    Chf[fb + 1 * 8] = bfs(v1);
                    Chf[fb + 2 * 8] = bfs(v2);
                    Chf[fb + 3 * 8] = bfs(v3);
                }
            }
        }
    }
}

// ---------------------------------------------------------------------------
// Flash attention, LDS-free / barrier-free (round-19 version, reverted from
// round-20 LDS broadcast). QBLK=128, K/V frags loaded once per tile, shared
// across 2 q-frags. QK 1-term + exp2, PV 1-term, l via ones-MFMA. XCD-swizzled.
// ---------------------------------------------------------------------------
__global__ __launch_bounds__(256) void attn_mfma_kernel(
    const uint* __restrict__ qrow, const short* __restrict__ kf,
    const short* __restrict__ vf, uint* __restrict__ y)
{
    const int tid  = threadIdx.x;
    const int w    = tid >> 6;
    const int lane = tid & 63;
    const int x    = lane & 15;
    const int gl   = lane >> 4;

    const int orig = blockIdx.x;
    const int wgid = (orig & 7) * 64 + (orig >> 3);
    const int bh = wgid >> 4;
    const int b = bh >> 4, hh = bh & 15;
    const int t0 = (wgid & 15) * 128;

    i32x4 qhi[2][2];
#pragma unroll
    for (int qf = 0; qf < 2; ++qf) {
        const uint* qp = qrow + (size_t)(b * T_SEQ + t0 + 64 * qf + 16 * w + x) * 1024 + hh * 64;
#pragma unroll
        for (int ch = 0; ch < 2; ++ch) {
            uint4 a0 = *(const uint4*)(qp + 32 * ch + 4 * gl);
            uint4 a1 = *(const uint4*)(qp + 32 * ch + 16 + 4 * gl);
            qhi[qf][ch][0] = (int)prm(a0.y, a0.x, SELHI); qhi[qf][ch][1] = (int)prm(a0.w, a0.z, SELHI);
            qhi[qf][ch][2] = (int)prm(a1.y, a1.x, SELHI); qhi[qf][ch][3] = (int)prm(a1.w, a1.z, SELHI);
        }
    }

    const short* kb = kf + (size_t)bh * 128 * 2 * 512 + (size_t)lane * 8;
    const short* vb = vf + (size_t)bh * 64 * 4 * 512 + (size_t)lane * 8;

    i32x4 ones4;
    ones4[0] = ones4[1] = ones4[2] = ones4[3] = 0x3F803F80;  // 8x bf16 1.0

    f32x4 oacc[2][4], lacc[2];
#pragma unroll
    for (int qf = 0; qf < 2; ++qf) {
        lacc[qf] = (f32x4){0.f, 0.f, 0.f, 0.f};
#pragma unroll
        for (int i = 0; i < 4; ++i) oacc[qf][i] = (f32x4){0.f, 0.f, 0.f, 0.f};
    }

    for (int s0 = 0; s0 < T_SEQ; s0 += 64) {
        bf16x8 kh[4][2], vh[2][4];
#pragma unroll
        for (int sc = 0; sc < 4; ++sc)
#pragma unroll
            for (int ch = 0; ch < 2; ++ch)
                kh[sc][ch] = *(const bf16x8*)(kb + ((((size_t)(s0 >> 4) + sc) * 2 + ch) * 512));
#pragma unroll
        for (int ch = 0; ch < 2; ++ch)
#pragma unroll
            for (int dm = 0; dm < 4; ++dm)
                vh[ch][dm] = *(const bf16x8*)(vb + ((((size_t)(s0 >> 5) + ch) * 4 + dm) * 512));

#pragma unroll
        for (int qf = 0; qf < 2; ++qf) {
            f32x4 s4[4];
#pragma unroll
            for (int sc = 0; sc < 4; ++sc) {
                s4[sc] = (f32x4){0.f, 0.f, 0.f, 0.f};
                s4[sc] = __builtin_amdgcn_mfma_f32_16x16x32_bf16(kh[sc][0], asb(qhi[qf][0]), s4[sc], 0, 0, 0);
                s4[sc] = __builtin_amdgcn_mfma_f32_16x16x32_bf16(kh[sc][1], asb(qhi[qf][1]), s4[sc], 0, 0, 0);
            }
#pragma unroll
            for (int sc = 0; sc < 4; ++sc) {
                s4[sc][0] = __builtin_amdgcn_exp2f(s4[sc][0]);
                s4[sc][1] = __builtin_amdgcn_exp2f(s4[sc][1]);
                s4[sc][2] = __builtin_amdgcn_exp2f(s4[sc][2]);
                s4[sc][3] = __builtin_amdgcn_exp2f(s4[sc][3]);
            }
            i32x4 pfh[2];
#pragma unroll
            for (int c = 0; c < 2; ++c) {
                f32x4 pa = s4[2 * c], pb = s4[2 * c + 1];
                pfh[c][0] = (int)prm(__float_as_uint(pa[1]), __float_as_uint(pa[0]), SELHI);
                pfh[c][1] = (int)prm(__float_as_uint(pa[3]), __float_as_uint(pa[2]), SELHI);
                pfh[c][2] = (int)prm(__float_as_uint(pb[1]), __float_as_uint(pb[0]), SELHI);
                pfh[c][3] = (int)prm(__float_as_uint(pb[3]), __float_as_uint(pb[2]), SELHI);
            }
            lacc[qf] = __builtin_amdgcn_mfma_f32_16x16x32_bf16(asb(ones4), asb(pfh[0]), lacc[qf], 0, 0, 0);
            lacc[qf] = __builtin_amdgcn_mfma_f32_16x16x32_bf16(asb(ones4), asb(pfh[1]), lacc[qf], 0, 0, 0);
#pragma unroll
            for (int dm = 0; dm < 4; ++dm) {
                oacc[qf][dm] = __builtin_amdgcn_mfma_f32_16x16x32_bf16(vh[0][dm], asb(pfh[0]), oacc[qf][dm], 0, 0, 0);
                oacc[qf][dm] = __builtin_amdgcn_mfma_f32_16x16x32_bf16(vh[1][dm], asb(pfh[1]), oacc[qf][dm], 0, 0, 0);
            }
        }
    }

#pragma unroll
    for (int qf = 0; qf < 2; ++qf) {
        const float invl = 1.f / lacc[qf][0];
        const size_t mt = (size_t)((b * T_SEQ + t0) >> 4) + 4 * qf + w;
#pragma unroll
        for (int dm = 0; dm < 4; ++dm) {
            f32x4 o = oacc[qf][dm];
            const size_t addr = (mt * 32 + hh * 2 + (dm >> 1)) * 512
                              + (size_t)lane * 8 + 4 * (dm & 1);
            uint4 pk;
            pk.x = packsplit(o[0] * invl); pk.y = packsplit(o[1] * invl);
            pk.z = packsplit(o[2] * invl); pk.w = packsplit(o[3] * invl);
            *(uint4*)&y[addr] = pk;
        }
    }
}

// ---------------------------------------------------------------------------
// LayerNorm; input frag-packed u32, output frag-packed u32 (for MFMA out GEMM).
// ---------------------------------------------------------------------------
__global__ __launch_bounds__(256) void ln_kernel(
    const uint* __restrict__ h, const float* __restrict__ gamma,
    const float* __restrict__ beta, uint* __restrict__ outp)
{
    const int row = blockIdx.x;
    const int tid = threadIdx.x;

    const size_t addr = ((size_t)(row >> 4) * 32 + (tid >> 3)) * 512
                      + (size_t)((tid & 3) * 16 + (row & 15)) * 8
                      + 4 * ((tid >> 2) & 1);
    uint4 u = *(const uint4*)&h[addr];
    float4 v;
    v.x = unpack2(u.x); v.y = unpack2(u.y); v.z = unpack2(u.z); v.w = unpack2(u.w);

    float s  = v.x + v.y + v.z + v.w;
    float ss = v.x * v.x + v.y * v.y + v.z * v.z + v.w * v.w;
#pragma unroll
    for (int off = 1; off < 64; off <<= 1) {
        s  += __shfl_xor(s, off);
        ss += __shfl_xor(ss, off);
    }
    __shared__ float rs[4], rss[4];
    const int wid = tid >> 6;
    if ((tid & 63) == 0) { rs[wid] = s; rss[wid] = ss; }
    __syncthreads();
    s  = rs[0] + rs[1] + rs[2] + rs[3];
    ss = rss[0] + rss[1] + rss[2] + rss[3];

    const float mu   = s * (1.f / (float)CDIM);
    const float var  = ss * (1.f / (float)CDIM) - mu * mu;
    const float rstd = rsqrtf(var + 1e-5f);

    const float4 g  = *(const float4*)&gamma[tid * 4];
    const float4 be = *(const float4*)&beta[tid * 4];
    uint4 pk;
    pk.x = packsplit((v.x - mu) * rstd * g.x + be.x);
    pk.y = packsplit((v.y - mu) * rstd * g.y + be.y);
    pk.z = packsplit((v.z - mu) * rstd * g.z + be.z);
    pk.w = packsplit((v.w - mu) * rstd * g.w + be.w);
    *(uint4*)&outp[addr] = pk;   // same frag-packed layout as input
}

// ---------------------------------------------------------------------------
extern "C" void kernel_launch(void* const* d_in, const int* in_sizes, int n_in,
                              void* d_out, int out_size, void* d_ws, size_t ws_size,
                              hipStream_t stream)
{
    const float* x      = (const float*)d_in[0];
    const float* W_emb  = (const float*)d_in[1];
    const float* b_emb  = (const float*)d_in[2];
    const float* pos    = (const float*)d_in[3];
    const float* Wqkv   = (const float*)d_in[4];
    const float* bqkv   = (const float*)d_in[5];
    const float* Wproj  = (const float*)d_in[6];
    const float* bproj  = (const float*)d_in[7];
    const float* gamma  = (const float*)d_in[8];
    const float* beta   = (const float*)d_in[9];
    const float* W_out  = (const float*)d_in[10];
    const float* b_out  = (const float*)d_in[11];
    float* out = (float*)d_out;

    uint* h    = (uint*)d_ws;                       // [4096][1024] frag-packed
    uint* qrow = h + (size_t)MROWS * CDIM;          // Q row-major packed; reused as LN output
    uint* y    = qrow + (size_t)MROWS * CDIM;       // [4096][1024] frag-packed (attn out)
    short* kf  = (short*)(y + (size_t)MROWS * CDIM);            // 32*128*2*512 bf16
    short* vfb = kf + (size_t)32 * 128 * 2 * 512;               // 32*64*4*512 bf16
    short* hf  = vfb + (size_t)32 * 64 * 4 * 512;   // h hi-only bf16 frags (4096x1024)
    short* Bqh = hf + (size_t)MROWS * CDIM;
    short* Bph = Bqh + (size_t)3 * CDIM * CDIM;
    short* Bpl = Bph + (size_t)CDIM * CDIM;
    short* Eh  = Bpl + (size_t)CDIM * CDIM;         // W_emb hi  (256x1024)
    short* El  = Eh  + (size_t)VDIM * CDIM;         // W_emb lo
    short* Oh  = El  + (size_t)VDIM * CDIM;         // W_out hi  (1024x256)
    short* Ol  = Oh  + (size_t)CDIM * VDIM;         // W_out lo
    uint*  xpf = (uint*)(Ol + (size_t)CDIM * VDIM); // x frag-packed (4096x256)

    const dim3 blk(256);
    const int nattn = (T_SEQ / 128) * BATCH * NHEAD;  // 512 blocks, 1-D swizzled

    // ---- embed: h(frag + hi-frag) = x @ W_emb + b_emb + pos, via MFMA ----
    packx_kernel<<<dim3(MROWS * (VDIM / 4) / 256), blk, 0, stream>>>(x, xpf);
    wsplit_kernel<<<dim3(CDIM / 64, VDIM / 16), blk, 0, stream>>>(W_emb, Eh, El, CDIM, VDIM);
    gemm_mfma_kernel<3, 4><<<dim3(CDIM / 128, MROWS / 128), blk, 0, stream>>>(
        xpf, nullptr, Eh, El, b_emb, pos, h, hf, MROWS, CDIM, VDIM, 2);

    for (int l = 0; l < NLAYER; ++l) {
        wsplit2_kernel<<<dim3(64, CDIM / 16), blk, 0, stream>>>(
            Wqkv + (size_t)l * CDIM * 3 * CDIM, Bqh,
            Wproj + (size_t)l * CDIM * CDIM, Bph, Bpl);
        gemm_lds1_kernel<<<dim3(3 * CDIM / 128, MROWS / 128), blk, 0, stream>>>(
            hf, Bqh, bqkv + (size_t)l * 3 * CDIM, qrow, kf, vfb, MROWS, 3 * CDIM, CDIM);
        attn_mfma_kernel<<<dim3(nattn), blk, 0, stream>>>(qrow, kf, vfb, y);
        // proj: NI=2 -> 128x64 tiles, 512 blocks (2 blocks/CU)
        gemm_mfma_kernel<3, 2><<<dim3(CDIM / 64, MROWS / 128), blk, 0, stream>>>(
            y, nullptr, Bph, Bpl, bproj + (size_t)l * CDIM, nullptr,
            h, hf, MROWS, CDIM, CDIM, 2);
    }

    // ---- LN (frag->frag, into qrow) + final out GEMM via MFMA ----
    ln_kernel<<<dim3(MROWS), blk, 0, stream>>>(h, gamma, beta, qrow);
    wsplit_kernel<<<dim3(VDIM / 64, CDIM / 16), blk, 0, stream>>>(W_out, Oh, Ol, VDIM, CDIM);
    // final: NI=1 -> 128x32 tiles, 256 blocks
    gemm_mfma_kernel<3, 1><<<dim3(VDIM / 32, MROWS / 128), blk, 0, stream>>>(
        qrow, nullptr, Oh, Ol, b_out, nullptr, (uint*)out, nullptr, MROWS, VDIM, CDIM, 0);
}